// Round 1
// baseline (74.853 us; speedup 1.0000x reference)
//
#include <hip/hip_runtime.h>
#include <math.h>

#pragma clang fp contract(off)

#define HH 96
#define WW 96
#define NV 9120          // 95*96 vertical candidates (global index base for horizontal)
#define NPIX 9216
#define TT 8             // pixel tile side
#define TB 12            // tiles per dimension (96/8)
#define NBLK 144         // TB*TB
#define CR 19            // cell halo region side = TT + 11  (floor cells +-4 scan)
#define NCL 361          // CR*CR
#define CSTR 5           // float4 stride per cell: 4 slots + 1 pad (bank spread)
#define SENT_D 3.4e38f
#define SENT_J 0x7fffffff

// ring offset for chebyshev ring R, perimeter index q in [0, 8R)
__device__ __forceinline__ void ring_off(int R, int q, int& dr, int& dc){
  int side = 2*R + 1;
  if (q < side){ dr = -R; dc = q - R; }
  else if (q < 2*side){ dr = R; dc = q - side - R; }
  else {
    int q2 = q - 2*side, half = side - 2;
    if (q2 < half){ dr = q2 - R + 1; dc = -R; }
    else          { dr = q2 - half - R + 1; dc = R; }
  }
}

// central-difference normal of pred at integer pixel (i,j) — same as old k_prep
__device__ __forceinline__ float2 nrm_at(const float* __restrict__ PR, int i, int j){
  float gr, gc;
  if (i == 0)         gr = PR[WW+j] - PR[j];
  else if (i == HH-1) gr = PR[(HH-1)*WW+j] - PR[(HH-2)*WW+j];
  else                gr = (PR[(i+1)*WW+j] - PR[(i-1)*WW+j]) / 2.0f;
  if (j == 0)         gc = PR[i*WW+1] - PR[i*WW];
  else if (j == WW-1) gc = PR[i*WW+WW-1] - PR[i*WW+WW-2];
  else                gc = (PR[i*WW+j+1] - PR[i*WW+j-1]) / 2.0f;
  return make_float2(gr, gc);
}

// ---- fused: per 8x8-pixel tile, rebuild cell halo in LDS, NN+dot for the
// ---- tile's candidates (+2 top/left halo), pixel gather from LDS ----------
__global__ __launch_bounds__(256) void k_fused(
    const float* __restrict__ PR, const float* __restrict__ GT,
    float* __restrict__ tmp, double* __restrict__ pvPart){
#pragma clang fp contract(off)
  __shared__ float4 cellS[NCL*CSTR];          // 28880 B
  __shared__ float2 dV[TT+2][TT];             // vertical cand: (r, masked dot)
  __shared__ float2 dH[TT][TT+2];             // horizontal cand: (c, masked dot)
  __shared__ double dred[256];
  const int tid = threadIdx.x;
  const int I0 = (blockIdx.x / TB) * TT;
  const int J0 = (blockIdx.x % TB) * TT;

  // ---- phase 1: gt-crossing cells for rows [I0-6, I0+TT+4], cols likewise.
  // OOB cells get all-sentinel slots so the scan needs no bounds checks.
  for (int idx = tid; idx < NCL; idx += 256){
    int ci = I0 - 6 + idx / CR;
    int cj = J0 - 6 + idx % CR;
    int cnt = 0;
    float4 slot[4];
    if (ci >= 0 && ci < HH && cj >= 0 && cj < WW){
      for (int s2 = 0; s2 < 2; ++s2){         // vertical sources i0=ci-1, ci
        int i0 = ci - 1 + s2;
        if (i0 >= 0 && i0 <= HH-2){
          float v1 = GT[i0*WW+cj], v2 = GT[(i0+1)*WW+cj];
          int mm = (v1 == 0.0f) || (v2 == 0.0f) || ((v1*v2) < 0.0f);
          if (mm){
            float a1f = fabsf(v1), a2f = fabsf(v2);
            float den = (a1f + a2f) + 1e-8f;  // left-assoc as reference
            float a = a1f / den;
            float i0f = (float)i0;
            float r = (v1 == 0.0f) ? i0f : ((v2 == 0.0f) ? (i0f + 1.0f) : (i0f + a));
            if ((int)floorf(r) == ci){        // lands in this cell row
              float c = (float)cj;
              float sg = (r*r) + (c*c);       // matches (gp**2).sum(1)
              slot[cnt++] = make_float4(r, c, sg, __int_as_float(i0*WW+cj));
            }
          }
        }
      }
      for (int s2 = 0; s2 < 2; ++s2){         // horizontal sources j0=cj-1, cj
        int j0 = cj - 1 + s2;
        if (j0 >= 0 && j0 <= WW-2){
          float v1 = GT[ci*WW+j0], v2 = GT[ci*WW+j0+1];
          int mm = (v1 == 0.0f) || (v2 == 0.0f) || ((v1*v2) < 0.0f);
          if (mm){
            float a1f = fabsf(v1), a2f = fabsf(v2);
            float den = (a1f + a2f) + 1e-8f;
            float b = a1f / den;
            float j0f = (float)j0;
            float c = (v1 == 0.0f) ? j0f : ((v2 == 0.0f) ? (j0f + 1.0f) : (j0f + b));
            if ((int)floorf(c) == cj){        // lands in this cell col
              float r = (float)ci;
              float sg = (r*r) + (c*c);
              slot[cnt++] = make_float4(r, c, sg,
                              __int_as_float(NV + ci*(WW-1) + j0));
            }
          }
        }
      }
    }
    for (int s2 = cnt; s2 < 4; ++s2)          // sentinels: never win, never tie
      slot[s2] = make_float4(0.0f, 0.0f, SENT_D, __int_as_float(SENT_J));
    float4* cb = &cellS[idx*CSTR];
    cb[0] = slot[0]; cb[1] = slot[1]; cb[2] = slot[2]; cb[3] = slot[3];
  }
  double accPix = 0.0;
  __syncthreads();

  // ---- phase 2: 160 candidates = vertical (TT+2)xTT + horizontal TTx(TT+2)
  if (tid < (TT+2)*TT + TT*(TT+2)){
    const bool isV = (tid < (TT+2)*TT);
    int a0, a1;
    bool valid;
    float rp = 0.0f, cp = 0.0f, v1 = 0.0f, v2 = 0.0f;
    if (isV){
      a0 = tid / TT; a1 = tid % TT;           // rows [I0-2, I0+TT-1], cols tile
      int i0 = I0 - 2 + a0, j = J0 + a1;
      valid = (i0 >= 0) && (i0 <= HH-2);
      if (valid){
        v1 = PR[i0*WW+j]; v2 = PR[(i0+1)*WW+j];
        float a1f = fabsf(v1), a2f = fabsf(v2);
        float den = (a1f + a2f) + 1e-8f;
        float a = a1f / den;
        float i0f = (float)i0;
        rp = (v1 == 0.0f) ? i0f : ((v2 == 0.0f) ? (i0f + 1.0f) : (i0f + a));
        cp = (float)j;
      }
    } else {
      int id2 = tid - (TT+2)*TT;
      a0 = id2 / (TT+2); a1 = id2 % (TT+2);   // rows tile, cols [J0-2, J0+TT-1]
      int i = I0 + a0, j0 = J0 - 2 + a1;
      valid = (j0 >= 0) && (j0 <= WW-2);
      if (valid){
        v1 = PR[i*WW+j0]; v2 = PR[i*WW+j0+1];
        float a1f = fabsf(v1), a2f = fabsf(v2);
        float den = (a1f + a2f) + 1e-8f;
        float b = a1f / den;
        float j0f = (float)j0;
        cp = (v1 == 0.0f) ? j0f : ((v2 == 0.0f) ? (j0f + 1.0f) : (j0f + b));
        rp = (float)i;
      }
    }
    float2 ov = make_float2(-1.0e9f, 0.0f);   // sentinel: floor never matches
    if (valid){
      int m = (v1 == 0.0f) || (v2 == 0.0f) || ((v1*v2) < 0.0f);
      float sp = (rp*rp) + (cp*cp);           // matches (pr_pts**2).sum(1) bits
      int fr = (int)floorf(rp), fc = (int)floorf(cp);
      int r0 = fr; if (r0 < 0) r0 = 0; if (r0 > HH-1) r0 = HH-1;
      int c0 = fc; if (c0 < 0) c0 = 0; if (c0 > WW-1) c0 = WW-1;
      int r1 = r0 + 1; if (r1 > HH-1) r1 = HH-1;
      int c1 = c0 + 1; if (c1 > WW-1) c1 = WW-1;
      float2 na = nrm_at(PR, r0, c0), nb = nrm_at(PR, r0, c1);
      float2 ncn = nrm_at(PR, r1, c0), nd = nrm_at(PR, r1, c1);
      float pa = PR[r0*WW+c0], pb = PR[r0*WW+c1];
      float pc = PR[r1*WW+c0], pd = PR[r1*WW+c1];
      float best = SENT_D, brg = 0.0f, bcg = 0.0f; int bjg = SENT_J;
      // local cell coords: fr in [I0-2, I0+TT], fc in [J0-2, J0+TT] -> +-4 in range
      int lr = fr - (I0 - 6), lc = fc - (J0 - 6);
      // inner 5x5 (radius 2), sentinel slots make it unconditional
      for (int dy = -2; dy <= 2; ++dy){
        for (int dx = -2; dx <= 2; ++dx){
          const float4* cb = &cellS[((lr+dy)*CR + (lc+dx))*CSTR];
          for (int s2 = 0; s2 < 4; ++s2){
            float4 gg = cb[s2];
            float cross = fmaf(cp, gg.y, rp*gg.x);   // same bits as brute force
            float d2 = (sp + gg.z) - (2.0f*cross);
            d2 = fmaxf(d2, 0.0f);
            int jg = __float_as_int(gg.w);
            if ((d2 < best) || ((d2 == best) && (jg < bjg))){
              best = d2; bjg = jg; brg = gg.x; bcg = gg.y;
            }
          }
        }
      }
      // outside radius 2 true d2 > 4 (computed >= 4-6e-6): skip if best <= 3.9999
      if (best > 3.9999f){
        for (int q = 0; q < 56; ++q){         // rings 3 (24) + 4 (32)
          int dr2, dc2;
          if (q < 24) ring_off(3, q, dr2, dc2);
          else        ring_off(4, q-24, dr2, dc2);
          const float4* cb = &cellS[((lr+dr2)*CR + (lc+dc2))*CSTR];
          for (int s2 = 0; s2 < 4; ++s2){
            float4 gg = cb[s2];
            float cross = fmaf(cp, gg.y, rp*gg.x);
            float d2 = (sp + gg.z) - (2.0f*cross);
            d2 = fmaxf(d2, 0.0f);
            int jg = __float_as_int(gg.w);
            if ((d2 < best) || ((d2 == best) && (jg < bjg))){
              best = d2; bjg = jg; brg = gg.x; bcg = gg.y;
            }
          }
        }
      }
      float ar = rp - (float)r0, ac = cp - (float)c0;
      float omr = 1.0f - ar, omc = 1.0f - ac;
      float wa = omr*omc, wb = omr*ac, wc = ar*omc, wd = ar*ac;
      float nr = (((na.x*wa) + (nb.x*wb)) + (ncn.x*wc)) + (nd.x*wd);
      float nc = (((na.y*wa) + (nb.y*wb)) + (ncn.y*wc)) + (nd.y*wd);
      float nrmv = sqrtf((nr*nr) + (nc*nc));
      float den = nrmv + 1e-8f;
      float nru = nr / den, ncu = nc / den;
      float drv = brg - rp, dcv = bcg - cp;
      float dotv = (drv*nru) + (dcv*ncu);
      int contrib = m && (best <= 9.0f);
      float vals = (((pa*wa) + (pb*wb)) + (pc*wc)) + (pd*wd);
      ov = make_float2(isV ? rp : cp, contrib ? dotv : 0.0f);
      // pix sum: each candidate owned by exactly one tile (its i0/j0 cell)
      bool owned = isV ? (a0 >= 2) : (a1 >= 2);
      if (owned && m) accPix = (double)vals;
    }
    if (isV) dV[a0][a1] = ov;
    else     dH[a0][a1] = ov;
  }
  dred[tid] = accPix;
  __syncthreads();

  // ---- phase 3: pixel gather (ordered scatter replication, same pass order)
  if (tid < TT*TT){
    int ti = tid / TT, tj = tid % TT;
    int i = I0 + ti, j = J0 + tj;
    float s = 0.0f;
    // pass1 vertical: wa = (1-ar) at (r0, j)
    for (int i0 = i-1; i0 <= i; ++i0){
      if (i0 < 0 || i0 > HH-2) continue;
      float2 e = dV[i0 - (I0-2)][tj];
      int rr0 = (int)floorf(e.x);
      if (rr0 == i){
        float ar = e.x - (float)rr0;
        float w = 1.0f - ar;
        s = s + (e.y * w);
      }
    }
    // pass1 horizontal: wa = (1-ac) at (i, c0)
    for (int j0 = j-1; j0 <= j; ++j0){
      if (j0 < 0 || j0 > WW-2) continue;
      float2 e = dH[ti][j0 - (J0-2)];
      int cc0 = (int)floorf(e.x);
      if (cc0 == j){
        float ac = e.x - (float)cc0;
        float w = 1.0f - ac;
        s = s + (e.y * w);
      }
    }
    // pass2 horizontal: wb = ac at (i, c0+1)
    for (int j0 = j-2; j0 <= j-1; ++j0){
      if (j0 < 0 || j0 > WW-2) continue;
      float2 e = dH[ti][j0 - (J0-2)];
      int cc0 = (int)floorf(e.x);
      if (cc0 == j-1){
        float ac = e.x - (float)cc0;
        s = s + (e.y * ac);
      }
    }
    // pass3 vertical: wc = ar at (r0+1, j)
    for (int i0 = i-2; i0 <= i-1; ++i0){
      if (i0 < 0 || i0 > HH-2) continue;
      float2 e = dV[i0 - (I0-2)][tj];
      int rr0 = (int)floorf(e.x);
      if (rr0 == i-1){
        float ar = e.x - (float)rr0;
        s = s + (e.y * ar);
      }
    }
    tmp[i*WW + j] = PR[i*WW + j] * s;
  }
  __syncthreads();
  // block-wide double reduce of pix partials (deterministic tree)
  for (int st = 128; st >= 1; st >>= 1){
    if (tid < st) dred[tid] += dred[tid + st];
    __syncthreads();
  }
  if (tid == 0) pvPart[blockIdx.x] = dred[0];
}

// ---- final: exact numpy pairwise sum over tmp (128 leaves x 72) + pix ----
__global__ __launch_bounds__(128) void k_final(
    const float* __restrict__ tmp, const double* __restrict__ pvPart,
    float* __restrict__ out){
#pragma clang fp contract(off)
  __shared__ float buf[128];
  __shared__ double dbuf[128];
  int t = threadIdx.x;
  const float4* a4 = (const float4*)(tmp + t*72);
  float4 x = a4[0], y = a4[1];
  float q0=x.x, q1=x.y, q2=x.z, q3=x.w, q4=y.x, q5=y.y, q6=y.z, q7=y.w;
  for (int i4 = 2; i4 < 18; i4 += 2){
    float4 u = a4[i4], v = a4[i4+1];
    q0 += u.x; q1 += u.y; q2 += u.z; q3 += u.w;
    q4 += v.x; q5 += v.y; q6 += v.z; q7 += v.w;
  }
  buf[t] = ((q0+q1)+(q2+q3)) + ((q4+q5)+(q6+q7));
  double pv = 0.0;
  for (int idx = t; idx < NBLK; idx += 128) pv += pvPart[idx];
  dbuf[t] = pv;
  __syncthreads();
  for (int st = 1; st < 128; st <<= 1){
    if ((t & (2*st - 1)) == 0){
      buf[t]  = buf[t]  + buf[t+st];
      dbuf[t] = dbuf[t] + dbuf[t+st];
    }
    __syncthreads();
  }
  if (t == 0) out[0] = buf[0] + (float)dbuf[0];
}

extern "C" void kernel_launch(void* const* d_in, const int* in_sizes, int n_in,
                              void* d_out, int out_size, void* d_ws, size_t ws_size,
                              hipStream_t stream){
  const float* pred = (const float*)d_in[0];
  const float* gt   = (const float*)d_in[1];
  float* out = (float*)d_out;

  char* w = (char*)d_ws;
  float*  tmp    = (float*)w;                  w += (size_t)NPIX*sizeof(float);
  double* pvPart = (double*)w;

  k_fused<<<dim3(NBLK), dim3(256), 0, stream>>>(pred, gt, tmp, pvPart);
  k_final<<<dim3(1), dim3(128), 0, stream>>>(tmp, pvPart, out);
}